// Round 11
// baseline (371.654 us; speedup 1.0000x reference)
//
#include <hip/hip_runtime.h>
#include <hip/hip_fp16.h>

#define TPB 256
#define STPB 512           // threads for scatter_sort (8 waves)
#define NW 8               // waves per scatter_sort block
#define BTPB 512           // threads for quarter_csr / expand_small
#define NBK 256            // bucket index space (dst >> 12); 245 used
#define BNODES 4096        // nodes per bucket
#define QNODES 1024        // nodes per quarter
#define CH 6144            // edges per scatter_sort chunk (~36 KB LDS -> 4 blocks/CU)
#define CAPB 45056         // fixed bucket capacity (mean 40960 + 20 sigma)
#define QSTG 12288         // quarter LDS stage capacity (48 KB; mean 10240 + 20 sigma)
#define CAP_L 262144       // cone row cap (|marked| ~ 92K mean)

typedef unsigned int uv4 __attribute__((ext_vector_type(4)));
union H8 { uv4 u; __half2 h2[4]; };

// ------- partition edges into fixed-capacity buckets; LDS counting sort, burst flush ---
// payload: (dstLow12 << 20) | src  (exactly 32 bits; requires n <= 2^20)
// Per-WAVE privatized counters/cursors (cnt8[8][256]): no cross-wave same-address LDS
// atomic serialization in either pass. Flush = per-bucket wave-cooperative run copy.
__global__ __launch_bounds__(STPB) void scatter_sort(const int* __restrict__ dst,
                                                     const int* __restrict__ src,
                                                     int* __restrict__ tails,
                                                     unsigned* __restrict__ bdata, int nE) {
    __shared__ unsigned stage[CH];               // 24 KB
    __shared__ int      cnt8[NW * NBK];          // 8 KB: counts -> per-wave cursors
    __shared__ int      cnt[NBK], sstart[NBK], cbase[NBK];   // 3 KB
    __shared__ int      wsum[STPB / 64];
    int t = threadIdx.x;
    int w = t >> 6;
    long base = (long)blockIdx.x * CH;
    int m = (int)(((long)nE - base < CH) ? (nE - base) : CH);
    for (int j = t; j < NW * NBK; j += STPB) cnt8[j] = 0;
    __syncthreads();
    // pass 1: per-wave bucket count, int4 loads
    for (int k = t * 4; k < m; k += STPB * 4) {
        if (k + 3 < m) {
            int4 d4 = *(const int4*)(dst + base + k);
            atomicAdd(&cnt8[w * NBK + (d4.x >> 12)], 1);
            atomicAdd(&cnt8[w * NBK + (d4.y >> 12)], 1);
            atomicAdd(&cnt8[w * NBK + (d4.z >> 12)], 1);
            atomicAdd(&cnt8[w * NBK + (d4.w >> 12)], 1);
        } else {
            int ke = (k + 4 < m) ? (k + 4) : m;
            for (int kk = k; kk < ke; ++kk)
                atomicAdd(&cnt8[w * NBK + (dst[base + kk] >> 12)], 1);
        }
    }
    __syncthreads();
    // totals + exclusive scan (shfl, waves 0-3) + per-bucket column scan -> cursors
    int v = 0, incl = 0;
    if (t < NBK) {
        v = 0;
#pragma unroll
        for (int ww = 0; ww < NW; ++ww) v += cnt8[ww * NBK + t];
        incl = v;
#pragma unroll
        for (int o = 1; o < 64; o <<= 1) {
            int u = __shfl_up(incl, o, 64);
            if ((t & 63) >= o) incl += u;
        }
        if ((t & 63) == 63) wsum[t >> 6] = incl;
    }
    __syncthreads();
    if (t < NBK) {
        int wadd = 0;
#pragma unroll
        for (int ww = 0; ww < 3; ++ww) wadd += (ww < (t >> 6)) ? wsum[ww] : 0;
        int ex = incl - v + wadd;
        sstart[t] = ex;
        cnt[t] = v;
        cbase[t] = v ? (t * CAPB + atomicAdd(&tails[t], v)) : 0;  // reserve global run
        int run = ex;                       // column scan: cnt8 -> per-wave cursors
#pragma unroll
        for (int ww = 0; ww < NW; ++ww) {
            int tmp = cnt8[ww * NBK + t];
            cnt8[ww * NBK + t] = run;
            run += tmp;
        }
    }
    __syncthreads();
    // pass 2: place into LDS at per-wave cursor (same edges per wave as pass 1)
    for (int k = t * 4; k < m; k += STPB * 4) {
        if (k + 3 < m) {
            int4 d4 = *(const int4*)(dst + base + k);
            int4 s4 = *(const int4*)(src + base + k);
            { int pos = atomicAdd(&cnt8[w * NBK + (d4.x >> 12)], 1);
              stage[pos] = ((unsigned)(d4.x & 4095) << 20) | (unsigned)s4.x; }
            { int pos = atomicAdd(&cnt8[w * NBK + (d4.y >> 12)], 1);
              stage[pos] = ((unsigned)(d4.y & 4095) << 20) | (unsigned)s4.y; }
            { int pos = atomicAdd(&cnt8[w * NBK + (d4.z >> 12)], 1);
              stage[pos] = ((unsigned)(d4.z & 4095) << 20) | (unsigned)s4.z; }
            { int pos = atomicAdd(&cnt8[w * NBK + (d4.w >> 12)], 1);
              stage[pos] = ((unsigned)(d4.w & 4095) << 20) | (unsigned)s4.w; }
        } else {
            int ke = (k + 4 < m) ? (k + 4) : m;
            for (int kk = k; kk < ke; ++kk) {
                int d = dst[base + kk], s = src[base + kk];
                int pos = atomicAdd(&cnt8[w * NBK + (d >> 12)], 1);
                stage[pos] = ((unsigned)(d & 4095) << 20) | (unsigned)s;
            }
        }
    }
    __syncthreads();
    // flush: wave w copies runs of buckets w, w+8, ... (contiguous src and dest)
    int lane = t & 63;
    for (int b2 = w; b2 < NBK; b2 += NW) {
        int c = cnt[b2], s0 = sstart[b2], g0 = cbase[b2];
        for (int k = lane; k < c; k += 64)
            bdata[g0 + k] = stage[s0 + k];
    }
}

// ------- per-QUARTER exact CSR build, XCD-swizzled (4 quarters of a bucket -> same XCD) -
// bid -> (xcd = bid&7, slot = bid>>3); bucket = (slot>>2)*8 + xcd; q = slot&3.
// Computes its own Pb; LDS-staged burst flush; fuses layer-1.
__global__ __launch_bounds__(BTPB) void quarter_csr(const unsigned* __restrict__ bdata,
                                                    const int* __restrict__ tails,
                                                    const float* __restrict__ x,
                                                    const float* __restrict__ W1,
                                                    int* __restrict__ rowptr,
                                                    __half* __restrict__ hs,
                                                    int* __restrict__ col, int n, int NB) {
    __shared__ int      off[QNODES];       // 4 KB (counts -> prefix -> cursor)
    __shared__ int      wsum[BTPB / 64];   // scan wave partials
    __shared__ int      wredQ[BTPB / 64];  // Qb reduction partials
    __shared__ int      wredP[BTPB / 64];  // Pb reduction partials
    __shared__ int      sQb, sTot, sPb;
    __shared__ unsigned stg[QSTG];         // 48 KB
    int bid = blockIdx.x, t = threadIdx.x;
    int xcd = bid & 7, slot = bid >> 3;
    int b = (slot >> 2) * 8 + xcd;
    int q = slot & 3;
    if (b >= NB) return;                   // uniform per block
    int e0 = b * CAPB, e1 = e0 + tails[b];
    for (int j = t; j < QNODES; j += BTPB) off[j] = 0;
    // Pb = sum of counts of buckets < b
    int partial = (t < b) ? tails[t] : 0;
#pragma unroll
    for (int o = 32; o > 0; o >>= 1) partial += __shfl_down(partial, o, 64);
    if ((t & 63) == 0) wredP[t >> 6] = partial;
    __syncthreads();                        // (1) off zeroed, wredP ready
    if (t == 0) {
        int s = 0;
#pragma unroll
        for (int w = 0; w < BTPB / 64; ++w) s += wredP[w];
        sPb = s;
    }
    // pass 1: count own quarter's degrees + tally edges of earlier quarters (Qb)
    int before = 0;
    for (int k = e0 + t * 4; k < e1; k += BTPB * 4) {
        if (k + 3 < e1) {
            uv4 p4 = *(const uv4*)(bdata + k);
#pragma unroll
            for (int z = 0; z < 4; ++z) {
                int j = (int)(p4[z] >> 20); int jq = j >> 10;
                if (jq == q) atomicAdd(&off[j & 1023], 1);
                before += (jq < q) ? 1 : 0;
            }
        } else {
            for (int kk = k; kk < e1; ++kk) {
                int j = (int)(bdata[kk] >> 20); int jq = j >> 10;
                if (jq == q) atomicAdd(&off[j & 1023], 1);
                before += (jq < q) ? 1 : 0;
            }
        }
    }
#pragma unroll
    for (int o = 32; o > 0; o >>= 1) before += __shfl_down(before, o, 64);
    if ((t & 63) == 0) wredQ[t >> 6] = before;
    __syncthreads();                        // (2) counts + wredQ + sPb ready
    if (t == 0) {
        int s = 0;
#pragma unroll
        for (int w = 0; w < BTPB / 64; ++w) s += wredQ[w];
        sQb = s;
    }
    // scan 1024 counts: thread t owns off[2t], off[2t+1]
    int a = off[2 * t], c = off[2 * t + 1];
    int s2 = a + c;
    int incl = s2;
#pragma unroll
    for (int o = 1; o < 64; o <<= 1) {
        int u = __shfl_up(incl, o, 64);
        if ((t & 63) >= o) incl += u;
    }
    if ((t & 63) == 63) wsum[t >> 6] = incl;
    __syncthreads();                        // (3) wsum + sQb visible
    int wadd = 0;
#pragma unroll
    for (int w = 0; w < BTPB / 64 - 1; ++w) wadd += (w < (t >> 6)) ? wsum[w] : 0;
    int pex = incl - s2 + wadd;
    off[2 * t]     = pex;
    off[2 * t + 1] = pex + a;
    if (t == BTPB - 1) sTot = pex + s2;     // quarter's total edge count
    int PbQb = sPb + sQb;
    // fused rowptr + layer-1 for own 2 nodes (deg = a, c; all in registers)
    {
        int node0 = (b << 12) + (q << 10) + 2 * t;
        float4 w0 = ((const float4*)W1)[0];
        float4 w1 = ((const float4*)W1)[1];
        if (node0 + 1 < n) {
            int2 rp; rp.x = PbQb + pex; rp.y = PbQb + pex + a;
            *(int2*)(rowptr + node0) = rp;
            float2 xv = *(const float2*)(x + node0);
            float dv0 = rsqrtf((float)a + 1.0f);
            float dv1 = rsqrtf((float)c + 1.0f);
            float xd0 = xv.x * dv0, xd1 = xv.y * dv1;
            H8 o0, o1;
            o0.h2[0] = __floats2half2_rn(xd0 * w0.x, xd0 * w0.y);
            o0.h2[1] = __floats2half2_rn(xd0 * w0.z, xd0 * w0.w);
            o0.h2[2] = __floats2half2_rn(xd0 * w1.x, xd0 * w1.y);
            o0.h2[3] = __floats2half2_rn(xd0 * w1.z, xd0 * w1.w);
            o1.h2[0] = __floats2half2_rn(xd1 * w0.x, xd1 * w0.y);
            o1.h2[1] = __floats2half2_rn(xd1 * w0.z, xd1 * w0.w);
            o1.h2[2] = __floats2half2_rn(xd1 * w1.x, xd1 * w1.y);
            o1.h2[3] = __floats2half2_rn(xd1 * w1.z, xd1 * w1.w);
            ((uv4*)hs)[node0]     = o0.u;
            ((uv4*)hs)[node0 + 1] = o1.u;
        } else {
            if (node0 <= n)     rowptr[node0]     = PbQb + pex;
            if (node0 + 1 <= n) rowptr[node0 + 1] = PbQb + pex + a;
            if (node0 < n) {
                float dv = rsqrtf((float)a + 1.0f);
                float xd = x[node0] * dv;
                H8 o;
                o.h2[0] = __floats2half2_rn(xd * w0.x, xd * w0.y);
                o.h2[1] = __floats2half2_rn(xd * w0.z, xd * w0.w);
                o.h2[2] = __floats2half2_rn(xd * w1.x, xd * w1.y);
                o.h2[3] = __floats2half2_rn(xd * w1.z, xd * w1.w);
                ((uv4*)hs)[node0] = o.u;
            }
        }
    }
    __syncthreads();                        // (4) prefixes finalized before cursor use
    // pass 2: fill own quarter into LDS stage at final offsets (L2-warm re-read)
    for (int k = e0 + t * 4; k < e1; k += BTPB * 4) {
        if (k + 3 < e1) {
            uv4 p4 = *(const uv4*)(bdata + k);
#pragma unroll
            for (int z = 0; z < 4; ++z) {
                int j = (int)(p4[z] >> 20);
                if ((j >> 10) == q) {
                    int pos = atomicAdd(&off[j & 1023], 1);
                    stg[pos] = p4[z] & 0xFFFFFu;
                }
            }
        } else {
            for (int kk = k; kk < e1; ++kk) {
                unsigned p = bdata[kk];
                int j = (int)(p >> 20);
                if ((j >> 10) == q) {
                    int pos = atomicAdd(&off[j & 1023], 1);
                    stg[pos] = p & 0xFFFFFu;
                }
            }
        }
    }
    __syncthreads();                        // (5)
    // burst flush: contiguous, full lines
    int tot = sTot;
    for (int k = t; k < tot; k += BTPB)
        col[PbQb + k] = (int)stg[k];
}

// ------- fused seed + tier-2 + tier-3 expansion: ONE block, exact tier boundaries -----
// Frontiers are tiny (64 -> ~700 -> ~7K rows); a single 512-thread block with an LDS
// queue tail and __syncthreads between tiers replaces 3 launches AND records exact
// boundaries qq[1..3], so downstream kernels need no mark filtering at all.
__global__ __launch_bounds__(BTPB) void expand_small(const int* __restrict__ idx, int B,
                                                     int* __restrict__ mark,
                                                     int* __restrict__ L,
                                                     int* __restrict__ qq,
                                                     const int* __restrict__ rowptr,
                                                     const int* __restrict__ col) {
    __shared__ int qt;
    int t = threadIdx.x;
    if (t == 0) qt = 0;
    __syncthreads();
    // seed (tag 1)
    if (t < B) {
        int u = idx[t];
        if (atomicCAS(&mark[u], 0, 1) == 0)
            L[atomicAdd(&qt, 1)] = u;
    }
    __syncthreads();
    int q1 = qt;
    // tier 2: expand rows [0, q1)  (appends land at >= q1, not revisited)
    for (int r = t; r < q1; r += BTPB) {
        int u = L[r];
        for (int k = rowptr[u], e = rowptr[u + 1]; k < e; ++k) {
            int s = col[k];
            if (mark[s] == 0 && atomicCAS(&mark[s], 0, 2) == 0)
                L[atomicAdd(&qt, 1)] = s;
        }
    }
    __syncthreads();
    int q2 = qt;
    // tier 3: expand rows [q1, q2)
    for (int r = q1 + t; r < q2; r += BTPB) {
        int u = L[r];
        for (int k = rowptr[u], e = rowptr[u + 1]; k < e; ++k) {
            int s = col[k];
            if (mark[s] == 0 && atomicCAS(&mark[s], 0, 3) == 0)
                L[atomicAdd(&qt, 1)] = s;
        }
    }
    __syncthreads();
    if (t == 0) { qq[1] = q1; qq[2] = q2; qq[3] = qt; qq[7] = qt; }
}

// ------- tier-4 expansion: rows [qq[2], qq[3]) -- all tag 3, no filter needed ---------
// Wave-aggregated enqueue: one atomicAdd(&qq[7]) per wave-iteration, coalesced appends.
__global__ __launch_bounds__(TPB) void expand_f(int* __restrict__ L, int* __restrict__ qq,
                                                const int* __restrict__ rowptr,
                                                const int* __restrict__ col,
                                                int* __restrict__ mark) {
    int lo = qq[2], hi = qq[3];
    int stride = gridDim.x * blockDim.x;
    int lane = threadIdx.x & 63;
    for (int r = lo + blockIdx.x * blockDim.x + threadIdx.x; r < hi; r += stride) {
        int u = L[r];
        int e0 = rowptr[u], e1 = rowptr[u + 1];
        for (int k = e0; k < e1; ++k) {
            int s = col[k];
            bool ok = (mark[s] == 0) && (atomicCAS(&mark[s], 0, 4) == 0);
            unsigned long long msk = __ballot(ok);
            if (msk) {
                int leader = __builtin_ctzll(msk);
                int cntw = __builtin_popcountll(msk);
                int basep = 0;
                if (lane == leader) basep = atomicAdd(&qq[7], cntw);
                basep = __shfl(basep, leader, 64);
                if (ok) {
                    int myoff = __builtin_popcountll(msk & ((1ull << lane) - 1ull));
                    L[basep + myoff] = s;
                }
            }
        }
    }
}

// ------- fused pull + node transform, 4 lanes per row, grid-stride --------------------
// Rows [0, qq[bidx]) -- exact tier-prefix bound, NO mark filtering (L is tier-ordered).
// Group-uniform control flow => intra-group __shfl_xor reduction is safe.
__global__ __launch_bounds__(TPB) void pull_tier(const int* __restrict__ L,
                          const int* __restrict__ qq, int bidx,
                          const int* __restrict__ rowptr, const int* __restrict__ col,
                          const __half* __restrict__ hs_in, const float* __restrict__ bias,
                          const float* __restrict__ W, __half* __restrict__ hs_out) {
    int nrows = qq[bidx];
    int gstride = gridDim.x * blockDim.x;
    const uv4* hv = (const uv4*)hs_in;
    for (int gidx = blockIdx.x * blockDim.x + threadIdx.x; (gidx >> 2) < nrows;
         gidx += gstride) {
        int r = gidx >> 2;
        int sl = gidx & 3;
        int u = L[r];
        float2 a0 = {0.f, 0.f}, a1 = {0.f, 0.f}, a2 = {0.f, 0.f}, a3 = {0.f, 0.f};
        int s = rowptr[u], e = rowptr[u + 1];
        for (int k = s + sl; k < e; k += 4) {
            H8 q; q.u = hv[col[k]];
            float2 b0 = __half22float2(q.h2[0]);
            float2 b1 = __half22float2(q.h2[1]);
            float2 b2 = __half22float2(q.h2[2]);
            float2 b3 = __half22float2(q.h2[3]);
            a0.x += b0.x; a0.y += b0.y; a1.x += b1.x; a1.y += b1.y;
            a2.x += b2.x; a2.y += b2.y; a3.x += b3.x; a3.y += b3.y;
        }
#pragma unroll
        for (int o = 1; o <= 2; o <<= 1) {
            a0.x += __shfl_xor(a0.x, o, 64); a0.y += __shfl_xor(a0.y, o, 64);
            a1.x += __shfl_xor(a1.x, o, 64); a1.y += __shfl_xor(a1.y, o, 64);
            a2.x += __shfl_xor(a2.x, o, 64); a2.y += __shfl_xor(a2.y, o, 64);
            a3.x += __shfl_xor(a3.x, o, 64); a3.y += __shfl_xor(a3.y, o, 64);
        }
        if (sl != 0) continue;
        H8 p; p.u = hv[u];                   // self term
        float2 s0 = __half22float2(p.h2[0]);
        float2 s1 = __half22float2(p.h2[1]);
        float2 s2 = __half22float2(p.h2[2]);
        float2 s3 = __half22float2(p.h2[3]);
        a0.x += s0.x; a0.y += s0.y; a1.x += s1.x; a1.y += s1.y;
        a2.x += s2.x; a2.y += s2.y; a3.x += s3.x; a3.y += s3.y;
        float d = rsqrtf((float)(e - s) + 1.0f);
        float t[8] = {a0.x * d, a0.y * d, a1.x * d, a1.y * d,
                      a2.x * d, a2.y * d, a3.x * d, a3.y * d};
#pragma unroll
        for (int k = 0; k < 8; ++k) {
            float v = t[k] + bias[k];
            t[k] = v > 0.0f ? v : 0.0f;
        }
        float h[8];
#pragma unroll
        for (int j = 0; j < 8; ++j) {
            float acc = 0.0f;
#pragma unroll
            for (int k = 0; k < 8; ++k) acc += t[k] * W[k * 8 + j];
            h[j] = acc * d;
        }
        H8 o;
        o.h2[0] = __floats2half2_rn(h[0], h[1]);
        o.h2[1] = __floats2half2_rn(h[2], h[3]);
        o.h2[2] = __floats2half2_rn(h[4], h[5]);
        o.h2[3] = __floats2half2_rn(h[6], h[7]);
        ((uv4*)hs_out)[u] = o.u;
    }
}

// ---------------- final: out[t][:] = dis*(sum+self) + b4, for the idx nodes ------
__global__ void pull_final(const int* __restrict__ idx, int B,
                           const int* __restrict__ rowptr, const int* __restrict__ col,
                           const __half* __restrict__ hs_in,
                           const float* __restrict__ b4, float* __restrict__ out) {
    int t = blockIdx.x * blockDim.x + threadIdx.x;
    if (t >= B) return;
    int u = idx[t];
    const uv4* hv = (const uv4*)hs_in;
    H8 p; p.u = hv[u];
    float2 a0 = __half22float2(p.h2[0]);
    float2 a1 = __half22float2(p.h2[1]);
    float2 a2 = __half22float2(p.h2[2]);
    float2 a3 = __half22float2(p.h2[3]);
    int s = rowptr[u], e = rowptr[u + 1];
    for (int k = s; k < e; ++k) {
        H8 q; q.u = hv[col[k]];
        float2 b0 = __half22float2(q.h2[0]);
        float2 b1 = __half22float2(q.h2[1]);
        float2 b2 = __half22float2(q.h2[2]);
        float2 b3 = __half22float2(q.h2[3]);
        a0.x += b0.x; a0.y += b0.y; a1.x += b1.x; a1.y += b1.y;
        a2.x += b2.x; a2.y += b2.y; a3.x += b3.x; a3.y += b3.y;
    }
    float d = rsqrtf((float)(e - s) + 1.0f);
    float* op = out + (size_t)t * 8;
    op[0] = a0.x * d + b4[0]; op[1] = a0.y * d + b4[1];
    op[2] = a1.x * d + b4[2]; op[3] = a1.y * d + b4[3];
    op[4] = a2.x * d + b4[4]; op[5] = a2.y * d + b4[5];
    op[6] = a3.x * d + b4[6]; op[7] = a3.y * d + b4[7];
}

extern "C" void kernel_launch(void* const* d_in, const int* in_sizes, int n_in,
                              void* d_out, int out_size, void* d_ws, size_t ws_size,
                              hipStream_t stream) {
    const float* x   = (const float*)d_in[0];
    const int*   ei  = (const int*)d_in[1];
    const int*   idx = (const int*)d_in[2];
    const float* W1  = (const float*)d_in[3];
    const float* b1  = (const float*)d_in[4];
    const float* W2  = (const float*)d_in[5];
    const float* b2  = (const float*)d_in[6];
    const float* W3  = (const float*)d_in[7];
    const float* b3  = (const float*)d_in[8];
    const float* W4  = (const float*)d_in[9];
    const float* b4  = (const float*)d_in[10];

    const int n = in_sizes[0];      // 1,000,000 nodes (n <= 2^20 for packing)
    const int E = in_sizes[1] / 2;  // 10,000,000 edges
    const int B = in_sizes[2];      // 64 graphs

    const int* src = ei;
    const int* dst = ei + E;

    const int NB = (n + BNODES - 1) / BNODES;            // 245 buckets

    // workspace (int elements): mark+tails+qq contiguous -> single memset
    size_t o_mark  = 0;
    size_t o_tails = o_mark  + (size_t)n;                // NBK counts
    size_t o_qq    = o_tails + NBK;                      // 16
    size_t o_rp    = o_qq    + 16;                       // n+1 (+pad)
    size_t o_hsA   = o_rp    + (size_t)n + 8;
    size_t o_L     = o_hsA   + (size_t)n * 4;
    size_t o_col   = o_L     + CAP_L;
    size_t o_bd    = o_col   + (size_t)E;                // bdata; hsB aliases its base

    int*      mark   = (int*)d_ws + o_mark;
    int*      tails  = (int*)d_ws + o_tails;
    int*      qq     = (int*)d_ws + o_qq;                // [1..3]=tier bounds, [7]=tail
    int*      rowptr = (int*)d_ws + o_rp;
    __half*   hsA    = (__half*)((int*)d_ws + o_hsA);
    int*      L      = (int*)d_ws + o_L;
    int*      col    = (int*)d_ws + o_col;
    unsigned* bdata  = (unsigned*)((int*)d_ws + o_bd);
    __half*   hsB    = (__half*)bdata;                   // bdata dead after quarter_csr

    const int gs  = (int)(((long)E + CH - 1) / CH);      // 1628
    const int gq  = ((NB + 7) / 8) * 32;                 // 992 swizzled quarter blocks

    // ---- init: one memset covers mark + tails + qq ----
    (void)hipMemsetAsync(mark, 0, ((size_t)n + NBK + 16) * sizeof(int), stream);

    // ---- bucket partition (per-wave privatized LDS counting sort, run-burst flush) ----
    scatter_sort<<<gs, STPB, 0, stream>>>(dst, src, tails, bdata, E);

    // ---- exact full CSR from XCD-swizzled quarter-buckets (fuses Pb + layer-1) ----
    quarter_csr<<<gq, BTPB, 0, stream>>>(bdata, tails, x, W1, rowptr, hsA, col, n, NB);

    // ---- cone expansion: seed+t2+t3 in ONE block (exact bounds), then t4 full-grid ----
    expand_small<<<1, BTPB, 0, stream>>>(idx, B, mark, L, qq, rowptr, col);
    expand_f<<<256, TPB, 0, stream>>>(L, qq, rowptr, col, mark);

    // ---- layers (4 lanes per row; exact tier-prefix bounds, no filtering) ----
    pull_tier<<<2048, TPB, 0, stream>>>(L, qq, 7, rowptr, col, hsA, b1, W2, hsB);
    pull_tier<<<128,  TPB, 0, stream>>>(L, qq, 3, rowptr, col, hsB, b2, W3, hsA);
    pull_tier<<<16,   TPB, 0, stream>>>(L, qq, 2, rowptr, col, hsA, b3, W4, hsB);
    pull_final<<<1, 64, 0, stream>>>(idx, B, rowptr, col, hsB, b4, (float*)d_out);
}

// Round 12
// 357.880 us; speedup vs baseline: 1.0385x; 1.0385x over previous
//
#include <hip/hip_runtime.h>
#include <hip/hip_fp16.h>

#define TPB 256
#define STPB 512           // threads for scatter_sort (8 waves)
#define NW 8               // waves per scatter_sort block
#define BTPB 512           // threads for quarter_csr
#define NBK 256            // bucket index space (dst >> 12); 245 used
#define BNODES 4096        // nodes per bucket
#define QNODES 1024        // nodes per quarter
#define CH 6144            // edges per scatter_sort chunk (~36 KB LDS -> 4 blocks/CU)
#define CAPB 45056         // fixed bucket capacity (mean 40960 + 20 sigma)
#define QSTG 12288         // quarter LDS stage capacity (48 KB; mean 10240 + 20 sigma)
#define CAP_L 262144       // cone row cap (|marked| ~ 92K mean)

typedef unsigned int uv4 __attribute__((ext_vector_type(4)));
union H8 { uv4 u; __half2 h2[4]; };

// ------- partition edges into fixed-capacity buckets; LDS counting sort, burst flush ---
// payload: (dstLow12 << 20) | src  (exactly 32 bits; requires n <= 2^20)
// Per-WAVE privatized counters/cursors (cnt8[8][256]): no cross-wave same-address LDS
// atomic serialization in either pass. Flush = per-bucket wave-cooperative run copy.
__global__ __launch_bounds__(STPB) void scatter_sort(const int* __restrict__ dst,
                                                     const int* __restrict__ src,
                                                     int* __restrict__ tails,
                                                     unsigned* __restrict__ bdata, int nE) {
    __shared__ unsigned stage[CH];               // 24 KB
    __shared__ int      cnt8[NW * NBK];          // 8 KB: counts -> per-wave cursors
    __shared__ int      cnt[NBK], sstart[NBK], cbase[NBK];   // 3 KB
    __shared__ int      wsum[STPB / 64];
    int t = threadIdx.x;
    int w = t >> 6;
    long base = (long)blockIdx.x * CH;
    int m = (int)(((long)nE - base < CH) ? (nE - base) : CH);
    for (int j = t; j < NW * NBK; j += STPB) cnt8[j] = 0;
    __syncthreads();
    // pass 1: per-wave bucket count, int4 loads
    for (int k = t * 4; k < m; k += STPB * 4) {
        if (k + 3 < m) {
            int4 d4 = *(const int4*)(dst + base + k);
            atomicAdd(&cnt8[w * NBK + (d4.x >> 12)], 1);
            atomicAdd(&cnt8[w * NBK + (d4.y >> 12)], 1);
            atomicAdd(&cnt8[w * NBK + (d4.z >> 12)], 1);
            atomicAdd(&cnt8[w * NBK + (d4.w >> 12)], 1);
        } else {
            int ke = (k + 4 < m) ? (k + 4) : m;
            for (int kk = k; kk < ke; ++kk)
                atomicAdd(&cnt8[w * NBK + (dst[base + kk] >> 12)], 1);
        }
    }
    __syncthreads();
    // totals + exclusive scan (shfl, waves 0-3) + per-bucket column scan -> cursors
    int v = 0, incl = 0;
    if (t < NBK) {
        v = 0;
#pragma unroll
        for (int ww = 0; ww < NW; ++ww) v += cnt8[ww * NBK + t];
        incl = v;
#pragma unroll
        for (int o = 1; o < 64; o <<= 1) {
            int u = __shfl_up(incl, o, 64);
            if ((t & 63) >= o) incl += u;
        }
        if ((t & 63) == 63) wsum[t >> 6] = incl;
    }
    __syncthreads();
    if (t < NBK) {
        int wadd = 0;
#pragma unroll
        for (int ww = 0; ww < 3; ++ww) wadd += (ww < (t >> 6)) ? wsum[ww] : 0;
        int ex = incl - v + wadd;
        sstart[t] = ex;
        cnt[t] = v;
        cbase[t] = v ? (t * CAPB + atomicAdd(&tails[t], v)) : 0;  // reserve global run
        int run = ex;                       // column scan: cnt8 -> per-wave cursors
#pragma unroll
        for (int ww = 0; ww < NW; ++ww) {
            int tmp = cnt8[ww * NBK + t];
            cnt8[ww * NBK + t] = run;
            run += tmp;
        }
    }
    __syncthreads();
    // pass 2: place into LDS at per-wave cursor (same edges per wave as pass 1)
    for (int k = t * 4; k < m; k += STPB * 4) {
        if (k + 3 < m) {
            int4 d4 = *(const int4*)(dst + base + k);
            int4 s4 = *(const int4*)(src + base + k);
            { int pos = atomicAdd(&cnt8[w * NBK + (d4.x >> 12)], 1);
              stage[pos] = ((unsigned)(d4.x & 4095) << 20) | (unsigned)s4.x; }
            { int pos = atomicAdd(&cnt8[w * NBK + (d4.y >> 12)], 1);
              stage[pos] = ((unsigned)(d4.y & 4095) << 20) | (unsigned)s4.y; }
            { int pos = atomicAdd(&cnt8[w * NBK + (d4.z >> 12)], 1);
              stage[pos] = ((unsigned)(d4.z & 4095) << 20) | (unsigned)s4.z; }
            { int pos = atomicAdd(&cnt8[w * NBK + (d4.w >> 12)], 1);
              stage[pos] = ((unsigned)(d4.w & 4095) << 20) | (unsigned)s4.w; }
        } else {
            int ke = (k + 4 < m) ? (k + 4) : m;
            for (int kk = k; kk < ke; ++kk) {
                int d = dst[base + kk], s = src[base + kk];
                int pos = atomicAdd(&cnt8[w * NBK + (d >> 12)], 1);
                stage[pos] = ((unsigned)(d & 4095) << 20) | (unsigned)s;
            }
        }
    }
    __syncthreads();
    // flush: wave w copies runs of buckets w, w+8, ... (contiguous src and dest)
    int lane = t & 63;
    for (int b2 = w; b2 < NBK; b2 += NW) {
        int c = cnt[b2], s0 = sstart[b2], g0 = cbase[b2];
        for (int k = lane; k < c; k += 64)
            bdata[g0 + k] = stage[s0 + k];
    }
}

// ------- per-QUARTER exact CSR build, XCD-swizzled (4 quarters of a bucket -> same XCD) -
// bid -> (xcd = bid&7, slot = bid>>3); bucket = (slot>>2)*8 + xcd; q = slot&3.
// Computes its own Pb; LDS-staged burst flush; fuses layer-1.
__global__ __launch_bounds__(BTPB) void quarter_csr(const unsigned* __restrict__ bdata,
                                                    const int* __restrict__ tails,
                                                    const float* __restrict__ x,
                                                    const float* __restrict__ W1,
                                                    int* __restrict__ rowptr,
                                                    __half* __restrict__ hs,
                                                    int* __restrict__ col, int n, int NB) {
    __shared__ int      off[QNODES];       // 4 KB (counts -> prefix -> cursor)
    __shared__ int      wsum[BTPB / 64];   // scan wave partials
    __shared__ int      wredQ[BTPB / 64];  // Qb reduction partials
    __shared__ int      wredP[BTPB / 64];  // Pb reduction partials
    __shared__ int      sQb, sTot, sPb;
    __shared__ unsigned stg[QSTG];         // 48 KB
    int bid = blockIdx.x, t = threadIdx.x;
    int xcd = bid & 7, slot = bid >> 3;
    int b = (slot >> 2) * 8 + xcd;
    int q = slot & 3;
    if (b >= NB) return;                   // uniform per block
    int e0 = b * CAPB, e1 = e0 + tails[b];
    for (int j = t; j < QNODES; j += BTPB) off[j] = 0;
    // Pb = sum of counts of buckets < b
    int partial = (t < b) ? tails[t] : 0;
#pragma unroll
    for (int o = 32; o > 0; o >>= 1) partial += __shfl_down(partial, o, 64);
    if ((t & 63) == 0) wredP[t >> 6] = partial;
    __syncthreads();                        // (1) off zeroed, wredP ready
    if (t == 0) {
        int s = 0;
#pragma unroll
        for (int w = 0; w < BTPB / 64; ++w) s += wredP[w];
        sPb = s;
    }
    // pass 1: count own quarter's degrees + tally edges of earlier quarters (Qb)
    int before = 0;
    for (int k = e0 + t * 4; k < e1; k += BTPB * 4) {
        if (k + 3 < e1) {
            uv4 p4 = *(const uv4*)(bdata + k);
#pragma unroll
            for (int z = 0; z < 4; ++z) {
                int j = (int)(p4[z] >> 20); int jq = j >> 10;
                if (jq == q) atomicAdd(&off[j & 1023], 1);
                before += (jq < q) ? 1 : 0;
            }
        } else {
            for (int kk = k; kk < e1; ++kk) {
                int j = (int)(bdata[kk] >> 20); int jq = j >> 10;
                if (jq == q) atomicAdd(&off[j & 1023], 1);
                before += (jq < q) ? 1 : 0;
            }
        }
    }
#pragma unroll
    for (int o = 32; o > 0; o >>= 1) before += __shfl_down(before, o, 64);
    if ((t & 63) == 0) wredQ[t >> 6] = before;
    __syncthreads();                        // (2) counts + wredQ + sPb ready
    if (t == 0) {
        int s = 0;
#pragma unroll
        for (int w = 0; w < BTPB / 64; ++w) s += wredQ[w];
        sQb = s;
    }
    // scan 1024 counts: thread t owns off[2t], off[2t+1]
    int a = off[2 * t], c = off[2 * t + 1];
    int s2 = a + c;
    int incl = s2;
#pragma unroll
    for (int o = 1; o < 64; o <<= 1) {
        int u = __shfl_up(incl, o, 64);
        if ((t & 63) >= o) incl += u;
    }
    if ((t & 63) == 63) wsum[t >> 6] = incl;
    __syncthreads();                        // (3) wsum + sQb visible
    int wadd = 0;
#pragma unroll
    for (int w = 0; w < BTPB / 64 - 1; ++w) wadd += (w < (t >> 6)) ? wsum[w] : 0;
    int pex = incl - s2 + wadd;
    off[2 * t]     = pex;
    off[2 * t + 1] = pex + a;
    if (t == BTPB - 1) sTot = pex + s2;     // quarter's total edge count
    int PbQb = sPb + sQb;
    // fused rowptr + layer-1 for own 2 nodes (deg = a, c; all in registers)
    {
        int node0 = (b << 12) + (q << 10) + 2 * t;
        float4 w0 = ((const float4*)W1)[0];
        float4 w1 = ((const float4*)W1)[1];
        if (node0 + 1 < n) {
            int2 rp; rp.x = PbQb + pex; rp.y = PbQb + pex + a;
            *(int2*)(rowptr + node0) = rp;
            float2 xv = *(const float2*)(x + node0);
            float dv0 = rsqrtf((float)a + 1.0f);
            float dv1 = rsqrtf((float)c + 1.0f);
            float xd0 = xv.x * dv0, xd1 = xv.y * dv1;
            H8 o0, o1;
            o0.h2[0] = __floats2half2_rn(xd0 * w0.x, xd0 * w0.y);
            o0.h2[1] = __floats2half2_rn(xd0 * w0.z, xd0 * w0.w);
            o0.h2[2] = __floats2half2_rn(xd0 * w1.x, xd0 * w1.y);
            o0.h2[3] = __floats2half2_rn(xd0 * w1.z, xd0 * w1.w);
            o1.h2[0] = __floats2half2_rn(xd1 * w0.x, xd1 * w0.y);
            o1.h2[1] = __floats2half2_rn(xd1 * w0.z, xd1 * w0.w);
            o1.h2[2] = __floats2half2_rn(xd1 * w1.x, xd1 * w1.y);
            o1.h2[3] = __floats2half2_rn(xd1 * w1.z, xd1 * w1.w);
            ((uv4*)hs)[node0]     = o0.u;
            ((uv4*)hs)[node0 + 1] = o1.u;
        } else {
            if (node0 <= n)     rowptr[node0]     = PbQb + pex;
            if (node0 + 1 <= n) rowptr[node0 + 1] = PbQb + pex + a;
            if (node0 < n) {
                float dv = rsqrtf((float)a + 1.0f);
                float xd = x[node0] * dv;
                H8 o;
                o.h2[0] = __floats2half2_rn(xd * w0.x, xd * w0.y);
                o.h2[1] = __floats2half2_rn(xd * w0.z, xd * w0.w);
                o.h2[2] = __floats2half2_rn(xd * w1.x, xd * w1.y);
                o.h2[3] = __floats2half2_rn(xd * w1.z, xd * w1.w);
                ((uv4*)hs)[node0] = o.u;
            }
        }
    }
    __syncthreads();                        // (4) prefixes finalized before cursor use
    // pass 2: fill own quarter into LDS stage at final offsets (L2-warm re-read)
    for (int k = e0 + t * 4; k < e1; k += BTPB * 4) {
        if (k + 3 < e1) {
            uv4 p4 = *(const uv4*)(bdata + k);
#pragma unroll
            for (int z = 0; z < 4; ++z) {
                int j = (int)(p4[z] >> 20);
                if ((j >> 10) == q) {
                    int pos = atomicAdd(&off[j & 1023], 1);
                    stg[pos] = p4[z] & 0xFFFFFu;
                }
            }
        } else {
            for (int kk = k; kk < e1; ++kk) {
                unsigned p = bdata[kk];
                int j = (int)(p >> 20);
                if ((j >> 10) == q) {
                    int pos = atomicAdd(&off[j & 1023], 1);
                    stg[pos] = p & 0xFFFFFu;
                }
            }
        }
    }
    __syncthreads();                        // (5)
    // burst flush: contiguous, full lines
    int tot = sTot;
    for (int k = t; k < tot; k += BTPB)
        col[PbQb + k] = (int)stg[k];
}

// ---------------- seed: mark idx nodes (tag 1), record qq[1] ----------------
__global__ void seed_q(const int* __restrict__ idx, int B, int* __restrict__ mark,
                       int* __restrict__ L, int* __restrict__ qq) {
    __shared__ int qt;
    int t = threadIdx.x;
    if (t == 0) qt = 0;
    __syncthreads();
    if (t < B) {
        int u = idx[t];
        if (atomicCAS(&mark[u], 0, 1) == 0)
            L[atomicAdd(&qt, 1)] = u;
    }
    __syncthreads();
    if (t == 0) { qq[1] = qt; qq[7] = qt; }
}

// ------- tier expansion: rows [qq[loI], qq[hiI]) -> tag newTag ------------------------
// Wave-aggregated enqueue (one qq[7] atomic per wave-iter). If recI != 0, the LAST
// block to finish (done-counter) snapshots qq[recI] = qq[7] -- exact tier boundary
// with no extra launch. done counter is memset-zeroed each call.
__global__ __launch_bounds__(TPB) void expand_t(int* __restrict__ L, int* __restrict__ qq,
                                                int loI, int hiI, int newTag, int recI,
                                                int* __restrict__ done,
                                                const int* __restrict__ rowptr,
                                                const int* __restrict__ col,
                                                int* __restrict__ mark) {
    int lo = qq[loI], hi = qq[hiI];
    int stride = gridDim.x * blockDim.x;
    int lane = threadIdx.x & 63;
    for (int r = lo + blockIdx.x * blockDim.x + threadIdx.x; r < hi; r += stride) {
        int u = L[r];
        int e0 = rowptr[u], e1 = rowptr[u + 1];
        for (int k = e0; k < e1; ++k) {
            int s = col[k];
            bool ok = (mark[s] == 0) && (atomicCAS(&mark[s], 0, newTag) == 0);
            unsigned long long msk = __ballot(ok);
            if (msk) {
                int leader = __builtin_ctzll(msk);
                int cntw = __builtin_popcountll(msk);
                int basep = 0;
                if (lane == leader) basep = atomicAdd(&qq[7], cntw);
                basep = __shfl(basep, leader, 64);
                if (ok) {
                    int myoff = __builtin_popcountll(msk & ((1ull << lane) - 1ull));
                    L[basep + myoff] = s;
                }
            }
        }
    }
    if (recI) {
        __syncthreads();                   // all block appends issued (qq[7] atomics done)
        if (threadIdx.x == 0) {
            if (atomicAdd(done, 1) == (int)gridDim.x - 1)
                qq[recI] = atomicAdd(&qq[7], 0);   // atomic read: coherent final tail
        }
    }
}

// ------- fused pull + node transform, 4 lanes per row, grid-stride --------------------
// Rows [0, qq[bidx]) -- exact tier-prefix bound, NO mark filtering (L is tier-ordered).
// Group-uniform control flow => intra-group __shfl_xor reduction is safe.
__global__ __launch_bounds__(TPB) void pull_tier(const int* __restrict__ L,
                          const int* __restrict__ qq, int bidx,
                          const int* __restrict__ rowptr, const int* __restrict__ col,
                          const __half* __restrict__ hs_in, const float* __restrict__ bias,
                          const float* __restrict__ W, __half* __restrict__ hs_out) {
    int nrows = qq[bidx];
    int gstride = gridDim.x * blockDim.x;
    const uv4* hv = (const uv4*)hs_in;
    for (int gidx = blockIdx.x * blockDim.x + threadIdx.x; (gidx >> 2) < nrows;
         gidx += gstride) {
        int r = gidx >> 2;
        int sl = gidx & 3;
        int u = L[r];
        float2 a0 = {0.f, 0.f}, a1 = {0.f, 0.f}, a2 = {0.f, 0.f}, a3 = {0.f, 0.f};
        int s = rowptr[u], e = rowptr[u + 1];
        for (int k = s + sl; k < e; k += 4) {
            H8 q; q.u = hv[col[k]];
            float2 b0 = __half22float2(q.h2[0]);
            float2 b1 = __half22float2(q.h2[1]);
            float2 b2 = __half22float2(q.h2[2]);
            float2 b3 = __half22float2(q.h2[3]);
            a0.x += b0.x; a0.y += b0.y; a1.x += b1.x; a1.y += b1.y;
            a2.x += b2.x; a2.y += b2.y; a3.x += b3.x; a3.y += b3.y;
        }
#pragma unroll
        for (int o = 1; o <= 2; o <<= 1) {
            a0.x += __shfl_xor(a0.x, o, 64); a0.y += __shfl_xor(a0.y, o, 64);
            a1.x += __shfl_xor(a1.x, o, 64); a1.y += __shfl_xor(a1.y, o, 64);
            a2.x += __shfl_xor(a2.x, o, 64); a2.y += __shfl_xor(a2.y, o, 64);
            a3.x += __shfl_xor(a3.x, o, 64); a3.y += __shfl_xor(a3.y, o, 64);
        }
        if (sl != 0) continue;
        H8 p; p.u = hv[u];                   // self term
        float2 s0 = __half22float2(p.h2[0]);
        float2 s1 = __half22float2(p.h2[1]);
        float2 s2 = __half22float2(p.h2[2]);
        float2 s3 = __half22float2(p.h2[3]);
        a0.x += s0.x; a0.y += s0.y; a1.x += s1.x; a1.y += s1.y;
        a2.x += s2.x; a2.y += s2.y; a3.x += s3.x; a3.y += s3.y;
        float d = rsqrtf((float)(e - s) + 1.0f);
        float t[8] = {a0.x * d, a0.y * d, a1.x * d, a1.y * d,
                      a2.x * d, a2.y * d, a3.x * d, a3.y * d};
#pragma unroll
        for (int k = 0; k < 8; ++k) {
            float v = t[k] + bias[k];
            t[k] = v > 0.0f ? v : 0.0f;
        }
        float h[8];
#pragma unroll
        for (int j = 0; j < 8; ++j) {
            float acc = 0.0f;
#pragma unroll
            for (int k = 0; k < 8; ++k) acc += t[k] * W[k * 8 + j];
            h[j] = acc * d;
        }
        H8 o;
        o.h2[0] = __floats2half2_rn(h[0], h[1]);
        o.h2[1] = __floats2half2_rn(h[2], h[3]);
        o.h2[2] = __floats2half2_rn(h[4], h[5]);
        o.h2[3] = __floats2half2_rn(h[6], h[7]);
        ((uv4*)hs_out)[u] = o.u;
    }
}

// ---------------- final: out[t][:] = dis*(sum+self) + b4, 4 lanes per row ------
__global__ void pull_final(const int* __restrict__ idx, int B,
                           const int* __restrict__ rowptr, const int* __restrict__ col,
                           const __half* __restrict__ hs_in,
                           const float* __restrict__ b4, float* __restrict__ out) {
    int gidx = blockIdx.x * blockDim.x + threadIdx.x;
    int r = gidx >> 2;
    int sl = gidx & 3;
    if (r >= B) return;
    int u = idx[r];
    const uv4* hv = (const uv4*)hs_in;
    float2 a0 = {0.f, 0.f}, a1 = {0.f, 0.f}, a2 = {0.f, 0.f}, a3 = {0.f, 0.f};
    int s = rowptr[u], e = rowptr[u + 1];
    for (int k = s + sl; k < e; k += 4) {
        H8 q; q.u = hv[col[k]];
        float2 b0 = __half22float2(q.h2[0]);
        float2 b1 = __half22float2(q.h2[1]);
        float2 b2 = __half22float2(q.h2[2]);
        float2 b3 = __half22float2(q.h2[3]);
        a0.x += b0.x; a0.y += b0.y; a1.x += b1.x; a1.y += b1.y;
        a2.x += b2.x; a2.y += b2.y; a3.x += b3.x; a3.y += b3.y;
    }
#pragma unroll
    for (int o = 1; o <= 2; o <<= 1) {
        a0.x += __shfl_xor(a0.x, o, 64); a0.y += __shfl_xor(a0.y, o, 64);
        a1.x += __shfl_xor(a1.x, o, 64); a1.y += __shfl_xor(a1.y, o, 64);
        a2.x += __shfl_xor(a2.x, o, 64); a2.y += __shfl_xor(a2.y, o, 64);
        a3.x += __shfl_xor(a3.x, o, 64); a3.y += __shfl_xor(a3.y, o, 64);
    }
    if (sl != 0) return;
    H8 p; p.u = hv[u];
    float2 s0 = __half22float2(p.h2[0]);
    float2 s1 = __half22float2(p.h2[1]);
    float2 s2 = __half22float2(p.h2[2]);
    float2 s3 = __half22float2(p.h2[3]);
    a0.x += s0.x; a0.y += s0.y; a1.x += s1.x; a1.y += s1.y;
    a2.x += s2.x; a2.y += s2.y; a3.x += s3.x; a3.y += s3.y;
    float d = rsqrtf((float)(e - s) + 1.0f);
    float* op = out + (size_t)r * 8;
    op[0] = a0.x * d + b4[0]; op[1] = a0.y * d + b4[1];
    op[2] = a1.x * d + b4[2]; op[3] = a1.y * d + b4[3];
    op[4] = a2.x * d + b4[4]; op[5] = a2.y * d + b4[5];
    op[6] = a3.x * d + b4[6]; op[7] = a3.y * d + b4[7];
}

extern "C" void kernel_launch(void* const* d_in, const int* in_sizes, int n_in,
                              void* d_out, int out_size, void* d_ws, size_t ws_size,
                              hipStream_t stream) {
    const float* x   = (const float*)d_in[0];
    const int*   ei  = (const int*)d_in[1];
    const int*   idx = (const int*)d_in[2];
    const float* W1  = (const float*)d_in[3];
    const float* b1  = (const float*)d_in[4];
    const float* W2  = (const float*)d_in[5];
    const float* b2  = (const float*)d_in[6];
    const float* W3  = (const float*)d_in[7];
    const float* b3  = (const float*)d_in[8];
    const float* W4  = (const float*)d_in[9];
    const float* b4  = (const float*)d_in[10];

    const int n = in_sizes[0];      // 1,000,000 nodes (n <= 2^20 for packing)
    const int E = in_sizes[1] / 2;  // 10,000,000 edges
    const int B = in_sizes[2];      // 64 graphs

    const int* src = ei;
    const int* dst = ei + E;

    const int NB = (n + BNODES - 1) / BNODES;            // 245 buckets

    // workspace (int elements): mark+tails+qq contiguous -> single memset
    size_t o_mark  = 0;
    size_t o_tails = o_mark  + (size_t)n;                // NBK counts
    size_t o_qq    = o_tails + NBK;                      // 16 (incl. done counters 8,9)
    size_t o_rp    = o_qq    + 16;                       // n+1 (+pad)
    size_t o_hsA   = o_rp    + (size_t)n + 8;
    size_t o_L     = o_hsA   + (size_t)n * 4;
    size_t o_col   = o_L     + CAP_L;
    size_t o_bd    = o_col   + (size_t)E;                // bdata; hsB aliases its base

    int*      mark   = (int*)d_ws + o_mark;
    int*      tails  = (int*)d_ws + o_tails;
    int*      qq     = (int*)d_ws + o_qq;                // [1..3]=tier bounds, [7]=tail
    int*      rowptr = (int*)d_ws + o_rp;
    __half*   hsA    = (__half*)((int*)d_ws + o_hsA);
    int*      L      = (int*)d_ws + o_L;
    int*      col    = (int*)d_ws + o_col;
    unsigned* bdata  = (unsigned*)((int*)d_ws + o_bd);
    __half*   hsB    = (__half*)bdata;                   // bdata dead after quarter_csr

    const int gs  = (int)(((long)E + CH - 1) / CH);      // 1628
    const int gq  = ((NB + 7) / 8) * 32;                 // 992 swizzled quarter blocks

    // ---- init: one memset covers mark + tails + qq (incl. done counters) ----
    (void)hipMemsetAsync(mark, 0, ((size_t)n + NBK + 16) * sizeof(int), stream);

    // ---- bucket partition (per-wave privatized LDS counting sort, run-burst flush) ----
    scatter_sort<<<gs, STPB, 0, stream>>>(dst, src, tails, bdata, E);

    // ---- exact full CSR from XCD-swizzled quarter-buckets (fuses Pb + layer-1) ----
    quarter_csr<<<gq, BTPB, 0, stream>>>(bdata, tails, x, W1, rowptr, hsA, col, n, NB);

    // ---- cone expansion: discrete tiers (full-device MLP), exact bounds via
    //      last-block-done snapshot (qq[8], qq[9] are the done counters) ----
    seed_q<<<1, 64, 0, stream>>>(idx, B, mark, L, qq);
    expand_t<<<2,   TPB, 0, stream>>>(L, qq, 0, 1, 2, 2, &qq[8], rowptr, col, mark);
    expand_t<<<8,   TPB, 0, stream>>>(L, qq, 1, 2, 3, 3, &qq[9], rowptr, col, mark);
    expand_t<<<256, TPB, 0, stream>>>(L, qq, 2, 3, 4, 0, &qq[10], rowptr, col, mark);

    // ---- layers (4 lanes per row; exact tier-prefix bounds, no filtering) ----
    pull_tier<<<2048, TPB, 0, stream>>>(L, qq, 7, rowptr, col, hsA, b1, W2, hsB);
    pull_tier<<<128,  TPB, 0, stream>>>(L, qq, 3, rowptr, col, hsB, b2, W3, hsA);
    pull_tier<<<16,   TPB, 0, stream>>>(L, qq, 2, rowptr, col, hsA, b3, W4, hsB);
    pull_final<<<1, TPB, 0, stream>>>(idx, B, rowptr, col, hsB, b4, (float*)d_out);
}